// Round 4
// baseline (5286.674 us; speedup 1.0000x reference)
//
#include <hip/hip_runtime.h>
#include <hip/hip_bf16.h>
#include <math.h>

namespace {

constexpr int Bn = 256;
constexpr int Tn = 128;
constexpr int Dn = 256;
constexpr int Hn = 512;
constexpr int BT = Bn * Tn;

constexpr int AP = 776;  // LDS row stride in bf16 elems (768+8): dword stride 388 = 4 mod 32
constexpr int GS = 36;   // gate staging stride (floats)
constexpr int FLAG_STRIDE = 32;  // ints between flags (128 B — own cache line)

typedef short bf8_t __attribute__((ext_vector_type(8)));
typedef float f32x4 __attribute__((ext_vector_type(4)));

__device__ __forceinline__ float sigm(float v) { return 1.0f / (1.0f + expf(-v)); }

__device__ __forceinline__ unsigned short f2bf(float f) {
  union { __hip_bfloat16 h; unsigned short u; } v;
  v.h = __float2bfloat16(f);
  return v.u;
}
__device__ __forceinline__ float bf2f(unsigned short u) {
  union { unsigned int i; float f; } v;
  v.i = ((unsigned int)u) << 16;
  return v.f;
}

// gamma_h[t][b][n] = exp(-relu(dt[m,:]@w_gh[:,n] + h_gh[n]))  (m = b*Tn + t)
__global__ __launch_bounds__(256) void k_gamma_h(const float* __restrict__ dt,
                                                 const float* __restrict__ w,
                                                 const float* __restrict__ bias,
                                                 float* __restrict__ outg) {
  __shared__ float As[64][17];
  __shared__ float Bs[16][64];
  int tid = threadIdx.x;
  int tx = tid & 15, ty = tid >> 4;
  int m0 = blockIdx.y * 64, n0 = blockIdx.x * 64;
  float acc[4][4] = {};
  for (int k0 = 0; k0 < Dn; k0 += 16) {
    {
      int ml = tid >> 2, kk = (tid & 3) * 4;
      float4 v = *(const float4*)(dt + (size_t)(m0 + ml) * Dn + k0 + kk);
      As[ml][kk + 0] = v.x; As[ml][kk + 1] = v.y;
      As[ml][kk + 2] = v.z; As[ml][kk + 3] = v.w;
    }
    {
      int kb = (tid >> 6) * 4, nl = tid & 63;
#pragma unroll
      for (int r = 0; r < 4; ++r)
        Bs[kb + r][nl] = w[(size_t)(k0 + kb + r) * Hn + n0 + nl];
    }
    __syncthreads();
#pragma unroll
    for (int kk = 0; kk < 16; ++kk) {
      float a[4], b[4];
#pragma unroll
      for (int i = 0; i < 4; ++i) a[i] = As[ty + 16 * i][kk];
#pragma unroll
      for (int j = 0; j < 4; ++j) b[j] = Bs[kk][tx + 16 * j];
#pragma unroll
      for (int i = 0; i < 4; ++i)
#pragma unroll
        for (int j = 0; j < 4; ++j) acc[i][j] += a[i] * b[j];
    }
    __syncthreads();
  }
#pragma unroll
  for (int j = 0; j < 4; ++j) {
    int n = n0 + tx + 16 * j;
    float bv = bias[n];
#pragma unroll
    for (int i = 0; i < 4; ++i) {
      int m = m0 + ty + 16 * i;
      int b = m >> 7, tt = m & (Tn - 1);
      float v = acc[i][j] + bv;
      outg[((size_t)tt * Bn + b) * Hn + n] = expf(-fmaxf(v, 0.0f));
    }
  }
}

// gamma_x GEMM fused with imputation; writes xs fp32 to xhats [T,B,D] and bf16 copy
__global__ __launch_bounds__(256) void k_xs(const float* __restrict__ dt,
                                            const float* __restrict__ w,
                                            const float* __restrict__ bias,
                                            const float* __restrict__ x,
                                            const float* __restrict__ mask,
                                            const float* __restrict__ xmean,
                                            float* __restrict__ out_xs,
                                            unsigned short* __restrict__ out_bf) {
  __shared__ float As[64][17];
  __shared__ float Bs[16][64];
  int tid = threadIdx.x;
  int tx = tid & 15, ty = tid >> 4;
  int m0 = blockIdx.y * 64, n0 = blockIdx.x * 64;
  float acc[4][4] = {};
  for (int k0 = 0; k0 < Dn; k0 += 16) {
    {
      int ml = tid >> 2, kk = (tid & 3) * 4;
      float4 v = *(const float4*)(dt + (size_t)(m0 + ml) * Dn + k0 + kk);
      As[ml][kk + 0] = v.x; As[ml][kk + 1] = v.y;
      As[ml][kk + 2] = v.z; As[ml][kk + 3] = v.w;
    }
    {
      int kb = (tid >> 6) * 4, nl = tid & 63;
#pragma unroll
      for (int r = 0; r < 4; ++r)
        Bs[kb + r][nl] = w[(size_t)(k0 + kb + r) * Dn + n0 + nl];
    }
    __syncthreads();
#pragma unroll
    for (int kk = 0; kk < 16; ++kk) {
      float a[4], b[4];
#pragma unroll
      for (int i = 0; i < 4; ++i) a[i] = As[ty + 16 * i][kk];
#pragma unroll
      for (int j = 0; j < 4; ++j) b[j] = Bs[kk][tx + 16 * j];
#pragma unroll
      for (int i = 0; i < 4; ++i)
#pragma unroll
        for (int j = 0; j < 4; ++j) acc[i][j] += a[i] * b[j];
    }
    __syncthreads();
  }
#pragma unroll
  for (int j = 0; j < 4; ++j) {
    int d = n0 + tx + 16 * j;
    float bv = bias[d];
    float xm = xmean[d];
#pragma unroll
    for (int i = 0; i < 4; ++i) {
      int m = m0 + ty + 16 * i;
      int b = m >> 7, tt = m & (Tn - 1);
      float g = expf(-fmaxf(acc[i][j] + bv, 0.0f));
      float imput = (tt == 0) ? xm
                              : g * x[(size_t)(m - 1) * Dn + d] + (1.0f - g) * xm;
      float xv = x[(size_t)m * Dn + d];
      float mv = mask[(size_t)m * Dn + d];
      float xsv = xv * mv + (1.0f - mv) * imput;
      size_t oi = ((size_t)tt * Bn + b) * Dn + d;
      out_xs[oi] = xsv;
      out_bf[oi] = f2bf(xsv);
    }
  }
}

// hdec_bf[0][b][h] = bf16(h0[h] * gammaT[0][b][h]); zero flag array
__global__ __launch_bounds__(256) void k_init(const float* __restrict__ h0,
                                              const float* __restrict__ gammaT,
                                              unsigned short* __restrict__ hdec,
                                              int* __restrict__ bar) {
  int i = blockIdx.x * 256 + threadIdx.x;  // [0, Bn*Hn) = [0][b][h]
  int h = i & (Hn - 1);
  hdec[i] = f2bf(h0[h] * gammaT[i]);
  if (i < 4 * 64 * FLAG_STRIDE) bar[i] = 0;
}

// Persistent MFMA scan: 256 blocks (1/CU), 4 waves. Block owns 64 b x (8 h x 4 gates).
// bf16 weights resident in LDS; A (xs||gamma*h) staged bf16 per step; c in regs.
// Inter-block sync: distributed per-block flag lines (no RMW contention).
__global__ __launch_bounds__(256, 1) void k_scan(
    const unsigned short* __restrict__ xs_bf,  // [T,B,D] bf16
    const float* __restrict__ gammaT,          // [T,B,H] fp32
    unsigned short* __restrict__ hdec_bf,      // [2,B,H] bf16 (pre-decayed h)
    unsigned short* __restrict__ h_bf,         // [T,B,H] bf16 (h1 history)
    const float* __restrict__ c0,              // [H]
    const float* __restrict__ W_ih,            // [4H, D] fp32
    const float* __restrict__ W_hh,            // [4H, H] fp32
    const float* __restrict__ b_ih, const float* __restrict__ b_hh,
    const float* __restrict__ tp,              // [B,T]
    const float* __restrict__ w_t, const float* __restrict__ h_t,
    int* __restrict__ bar) {
  __shared__ unsigned short Wlds[32 * AP];  // 48.5 KB
  __shared__ unsigned short Alds[64 * AP];  // 97 KB
  __shared__ float Gs[64 * GS];             // 9 KB
  int tid = threadIdx.x;
  int bt = blockIdx.x & 3;   // batch group
  int ht = blockIdx.x >> 2;  // h tile
  int b0 = bt * 64, h0b = ht * 8;

  // --- stage weights once: col c = g*8+hu, K-major bf16
  for (int idx = tid; idx < 32 * 192; idx += 256) {
    int c = idx / 192;
    int s = idx - c * 192;
    int kg = s * 4;
    int g = c >> 3, hu = c & 7;
    int jw = g * Hn + h0b + hu;
    float4 wv;
    if (kg < Dn) wv = *(const float4*)(W_ih + (size_t)jw * Dn + kg);
    else         wv = *(const float4*)(W_hh + (size_t)jw * Hn + (kg - Dn));
    unsigned int u01 = (unsigned int)f2bf(wv.x) | ((unsigned int)f2bf(wv.y) << 16);
    unsigned int u23 = (unsigned int)f2bf(wv.z) | ((unsigned int)f2bf(wv.w) << 16);
    *(unsigned int*)(&Wlds[(size_t)c * AP + kg]) = u01;
    *(unsigned int*)(&Wlds[(size_t)c * AP + kg + 2]) = u23;
  }

  // --- per-thread cell hoists (2 cells: (b0+tid/8, hu) and (+32, hu))
  int hu = tid & 7;
  int hcell = h0b + hu;
  float bias[4];
#pragma unroll
  for (int g = 0; g < 4; ++g) {
    int jw = g * Hn + hcell;
    bias[g] = b_ih[jw] + b_hh[jw];
  }
  float wtv = w_t[hcell], htv = h_t[hcell];
  float creg[2];
  creg[0] = creg[1] = c0[hcell];
  int brow[2] = {b0 + (tid >> 3), b0 + 32 + (tid >> 3)};
  int bloc[2] = {tid >> 3, 32 + (tid >> 3)};
  int* mybar = bar + bt * 64 * FLAG_STRIDE;  // 64 flags, one line each

  // --- MFMA lane mapping
  int lane = tid & 63, wv4 = tid >> 6;
  int ln = lane & 15, qd = lane >> 4;
  const unsigned short* abase = &Alds[(size_t)(wv4 * 16 + ln) * AP + qd * 8];
  const unsigned short* bb0 = &Wlds[(size_t)ln * AP + qd * 8];
  const unsigned short* bb1 = &Wlds[(size_t)(16 + ln) * AP + qd * 8];

  // --- pre-stage xs(0) into Alds (k < 256 region)
  {
    const float4* xsrc = (const float4*)(xs_bf + ((size_t)0 * Bn + b0) * Dn);
#pragma unroll
    for (int i = 0; i < 8; ++i) {
      int c = tid + 256 * i;
      *(float4*)(&Alds[(size_t)(c >> 5) * AP + (c & 31) * 8]) = xsrc[c];
    }
  }

  for (int t = 0; t < Tn; ++t) {
    // --- stage pre-decayed h (k >= 256 region)
    {
      const float4* hsrc =
          (const float4*)(hdec_bf + (size_t)(t & 1) * Bn * Hn + (size_t)b0 * Hn);
#pragma unroll
      for (int i = 0; i < 16; ++i) {
        int c = tid + 256 * i;
        int row = c >> 6, off = c & 63;
        float4 v = hsrc[c];
        *(float4*)(&Alds[(size_t)row * AP + 256 + off * 8]) = v;
      }
    }
    // --- prefetch epilogue operands (indep of barrier; overlaps MFMA)
    float gam0[2], gam1[2], tpv[2];
#pragma unroll
    for (int r = 0; r < 2; ++r) {
      int b = brow[r];
      gam0[r] = gammaT[((size_t)t * Bn + b) * Hn + hcell];
      gam1[r] = (t + 1 < Tn) ? gammaT[((size_t)(t + 1) * Bn + b) * Hn + hcell] : 0.f;
      tpv[r] = tp[(size_t)b * Tn + t];
    }
    __syncthreads();

    // --- MFMA: 24 k-steps x 2 n-tiles
    f32x4 acc0 = {0.f, 0.f, 0.f, 0.f};
    f32x4 acc1 = {0.f, 0.f, 0.f, 0.f};
#pragma unroll
    for (int ks = 0; ks < 24; ++ks) {
      bf8_t a = *(const bf8_t*)(abase + ks * 32);
      bf8_t b0f = *(const bf8_t*)(bb0 + ks * 32);
      bf8_t b1f = *(const bf8_t*)(bb1 + ks * 32);
      acc0 = __builtin_amdgcn_mfma_f32_16x16x32_bf16(a, b0f, acc0, 0, 0, 0);
      acc1 = __builtin_amdgcn_mfma_f32_16x16x32_bf16(a, b1f, acc1, 0, 0, 0);
    }

    // --- gates -> LDS (C layout: col=lane&15, row=quad*4+reg)
#pragma unroll
    for (int r = 0; r < 4; ++r) {
      int grow = wv4 * 16 + qd * 4 + r;
      Gs[grow * GS + ln] = acc0[r];
      Gs[grow * GS + 16 + ln] = acc1[r];
    }
    __syncthreads();  // Gs ready; also: all MFMA reads of Alds complete

    // --- LSTM cell, 2 cells/thread (prefetched operands)
#pragma unroll
    for (int r = 0; r < 2; ++r) {
      int b = brow[r];
      int bl = bloc[r];
      float ipre = Gs[bl * GS + hu] + bias[0];
      float fpre = Gs[bl * GS + 8 + hu] + bias[1];
      float gpre = Gs[bl * GS + 16 + hu] + bias[2];
      float opre = Gs[bl * GS + 24 + hu] + bias[3];
      float c1 = sigm(fpre) * (creg[r] * gam0[r]) + sigm(ipre) * tanhf(gpre);
      float gtv = sigm(tpv[r] * wtv + htv);
      float h1 = gtv * sigm(opre) * tanhf(c1);
      creg[r] = gtv * c1;
      h_bf[((size_t)t * Bn + b) * Hn + hcell] = f2bf(h1);
      if (t + 1 < Tn) {
        hdec_bf[(size_t)((t + 1) & 1) * Bn * Hn + (size_t)b * Hn + hcell] =
            f2bf(h1 * gam1[r]);
      }
    }

    if (t + 1 < Tn) {
      // --- pre-stage next xs into Alds (safe: MFMA reads done at Gs-sync)
      const float4* xsrc = (const float4*)(xs_bf + ((size_t)(t + 1) * Bn + b0) * Dn);
#pragma unroll
      for (int i = 0; i < 8; ++i) {
        int c = tid + 256 * i;
        *(float4*)(&Alds[(size_t)(c >> 5) * AP + (c & 31) * 8]) = xsrc[c];
      }

      // --- distributed flag barrier over this batch group's 64 blocks
      __threadfence();   // each thread drains its own global stores
      __syncthreads();   // all threads' fences complete
      if (tid == 0)
        __hip_atomic_store(&mybar[ht * FLAG_STRIDE], t + 1, __ATOMIC_RELEASE,
                           __HIP_MEMORY_SCOPE_AGENT);
      if (tid < 64) {
        int spins = 0;
        while (__hip_atomic_load(&mybar[tid * FLAG_STRIDE], __ATOMIC_RELAXED,
                                 __HIP_MEMORY_SCOPE_AGENT) < t + 1) {
          __builtin_amdgcn_s_sleep(1);
          if (++spins > 50000000) break;  // bail visibly rather than hang
        }
      }
      __syncthreads();
      __threadfence();   // acquire: make remote hdec stores visible to all threads
    }
  }
}

// Batched output head over all (t,b) rows; h1 read from bf16 history
__global__ __launch_bounds__(256) void k_head(const unsigned short* __restrict__ h_bf,
                                              const float* __restrict__ W1,
                                              const float* __restrict__ b1,
                                              const float* __restrict__ W2,
                                              const float* __restrict__ b2,
                                              float* __restrict__ outs) {
  __shared__ float sW1[Hn * 10];
  for (int i = threadIdx.x; i < Hn * 10; i += 256) sW1[i] = W1[i];
  __syncthreads();
  int idx = blockIdx.x * 256 + threadIdx.x;  // idx = tt*Bn + b
  const uint4* row = (const uint4*)(h_bf + (size_t)idx * Hn);
  float z1[10];
#pragma unroll
  for (int k = 0; k < 10; ++k) z1[k] = b1[k];
  for (int hq = 0; hq < Hn / 8; ++hq) {
    uint4 u = row[hq];
    float hv[8];
    hv[0] = bf2f(u.x & 0xffff); hv[1] = bf2f(u.x >> 16);
    hv[2] = bf2f(u.y & 0xffff); hv[3] = bf2f(u.y >> 16);
    hv[4] = bf2f(u.z & 0xffff); hv[5] = bf2f(u.z >> 16);
    hv[6] = bf2f(u.w & 0xffff); hv[7] = bf2f(u.w >> 16);
    int hb = hq * 8;
#pragma unroll
    for (int c = 0; c < 8; ++c)
#pragma unroll
      for (int k = 0; k < 10; ++k) z1[k] += hv[c] * sW1[(hb + c) * 10 + k];
  }
#pragma unroll
  for (int k = 0; k < 10; ++k) z1[k] = sigm(z1[k]);
  float z2[2];
#pragma unroll
  for (int c = 0; c < 2; ++c) {
    float v = b2[c];
#pragma unroll
    for (int k = 0; k < 10; ++k) v += z1[k] * W2[k * 2 + c];
    z2[c] = sigm(v);
  }
  float mx = fmaxf(z2[0], z2[1]);
  float e0 = expf(z2[0] - mx), e1 = expf(z2[1] - mx);
  float s = e0 + e1;
  outs[(size_t)idx * 2 + 0] = e0 / s;
  outs[(size_t)idx * 2 + 1] = e1 / s;
}

}  // namespace

extern "C" void kernel_launch(void* const* d_in, const int* in_sizes, int n_in,
                              void* d_out, int out_size, void* d_ws,
                              size_t ws_size, hipStream_t stream) {
  (void)in_sizes; (void)n_in; (void)out_size; (void)ws_size;
  const float* x     = (const float*)d_in[0];
  const float* dt    = (const float*)d_in[1];
  const float* mask  = (const float*)d_in[2];
  const float* tp    = (const float*)d_in[3];
  const float* xmean = (const float*)d_in[4];
  const float* h0    = (const float*)d_in[5];
  const float* c0    = (const float*)d_in[6];
  const float* w_gx  = (const float*)d_in[7];
  const float* h_gx  = (const float*)d_in[8];
  const float* w_gh  = (const float*)d_in[9];
  const float* h_gh  = (const float*)d_in[10];
  const float* w_t   = (const float*)d_in[11];
  const float* h_t   = (const float*)d_in[12];
  const float* W_ih  = (const float*)d_in[13];
  const float* W_hh  = (const float*)d_in[14];
  const float* b_ih  = (const float*)d_in[15];
  const float* b_hh  = (const float*)d_in[16];
  const float* oW1   = (const float*)d_in[17];
  const float* ob1   = (const float*)d_in[18];
  const float* oW2   = (const float*)d_in[19];
  const float* ob2   = (const float*)d_in[20];

  float* out  = (float*)d_out;
  float* outs = out;                        // [T,B,2]
  float* xhat = out + (size_t)Tn * Bn * 2;  // [T,B,D] fp32 (output 1)

  float* ws = (float*)d_ws;
  float* gammaT = ws;  // [T,B,H] fp32: 67.1 MB
  unsigned short* xs_bf   = (unsigned short*)(gammaT + (size_t)BT * Hn);  // 16.8 MB
  unsigned short* h_bf    = xs_bf + (size_t)BT * Dn;                      // 33.6 MB
  unsigned short* hdec_bf = h_bf + (size_t)BT * Hn;                       // 0.5 MB
  int* bar = (int*)(hdec_bf + 2 * (size_t)Bn * Hn);                       // 32 KB flags

  k_gamma_h<<<dim3(Hn / 64, BT / 64), 256, 0, stream>>>(dt, w_gh, h_gh, gammaT);
  k_xs<<<dim3(Dn / 64, BT / 64), 256, 0, stream>>>(dt, w_gx, h_gx, x, mask,
                                                   xmean, xhat, xs_bf);
  k_init<<<(Bn * Hn) / 256, 256, 0, stream>>>(h0, gammaT, hdec_bf, bar);
  k_scan<<<256, 256, 0, stream>>>(xs_bf, gammaT, hdec_bf, h_bf, c0, W_ih, W_hh,
                                  b_ih, b_hh, tp, w_t, h_t, bar);
  k_head<<<BT / 256, 256, 0, stream>>>(h_bf, oW1, ob1, oW2, ob2, outs);
}

// Round 5
// 1653.447 us; speedup vs baseline: 3.1974x; 3.1974x over previous
//
#include <hip/hip_runtime.h>
#include <hip/hip_bf16.h>
#include <math.h>

namespace {

constexpr int Bn = 256;
constexpr int Tn = 128;
constexpr int Dn = 256;
constexpr int Hn = 512;
constexpr int BT = Bn * Tn;

constexpr int AP = 776;   // LDS K-stride in bf16 (768+8); rows 16B-aligned
constexpr int GS = 68;    // gate tile stride (floats), 32 rows x 64 cols
constexpr int FLAG_STRIDE = 32;  // ints between flags (128 B lines)
constexpr int NGROUP = 8;        // batch groups (32 batches each)
constexpr int BLK_PER_GROUP = 32;

typedef short bf8_t __attribute__((ext_vector_type(8)));
typedef float f32x4 __attribute__((ext_vector_type(4)));

__device__ __forceinline__ float sigm(float v) { return 1.0f / (1.0f + expf(-v)); }

__device__ __forceinline__ unsigned short f2bf(float f) {
  union { __hip_bfloat16 h; unsigned short u; } v;
  v.h = __float2bfloat16(f);
  return v.u;
}
__device__ __forceinline__ float bf2f(unsigned short u) {
  union { unsigned int i; float f; } v;
  v.i = ((unsigned int)u) << 16;
  return v.f;
}

// gamma_h[t][b][n] = exp(-relu(dt[m,:]@w_gh[:,n] + h_gh[n]))  (m = b*Tn + t)
__global__ __launch_bounds__(256) void k_gamma_h(const float* __restrict__ dt,
                                                 const float* __restrict__ w,
                                                 const float* __restrict__ bias,
                                                 float* __restrict__ outg) {
  __shared__ float As[64][17];
  __shared__ float Bs[16][64];
  int tid = threadIdx.x;
  int tx = tid & 15, ty = tid >> 4;
  int m0 = blockIdx.y * 64, n0 = blockIdx.x * 64;
  float acc[4][4] = {};
  for (int k0 = 0; k0 < Dn; k0 += 16) {
    {
      int ml = tid >> 2, kk = (tid & 3) * 4;
      float4 v = *(const float4*)(dt + (size_t)(m0 + ml) * Dn + k0 + kk);
      As[ml][kk + 0] = v.x; As[ml][kk + 1] = v.y;
      As[ml][kk + 2] = v.z; As[ml][kk + 3] = v.w;
    }
    {
      int kb = (tid >> 6) * 4, nl = tid & 63;
#pragma unroll
      for (int r = 0; r < 4; ++r)
        Bs[kb + r][nl] = w[(size_t)(k0 + kb + r) * Hn + n0 + nl];
    }
    __syncthreads();
#pragma unroll
    for (int kk = 0; kk < 16; ++kk) {
      float a[4], b[4];
#pragma unroll
      for (int i = 0; i < 4; ++i) a[i] = As[ty + 16 * i][kk];
#pragma unroll
      for (int j = 0; j < 4; ++j) b[j] = Bs[kk][tx + 16 * j];
#pragma unroll
      for (int i = 0; i < 4; ++i)
#pragma unroll
        for (int j = 0; j < 4; ++j) acc[i][j] += a[i] * b[j];
    }
    __syncthreads();
  }
#pragma unroll
  for (int j = 0; j < 4; ++j) {
    int n = n0 + tx + 16 * j;
    float bv = bias[n];
#pragma unroll
    for (int i = 0; i < 4; ++i) {
      int m = m0 + ty + 16 * i;
      int b = m >> 7, tt = m & (Tn - 1);
      float v = acc[i][j] + bv;
      outg[((size_t)tt * Bn + b) * Hn + n] = expf(-fmaxf(v, 0.0f));
    }
  }
}

// gamma_x GEMM fused with imputation; writes xs fp32 to xhats [T,B,D] and bf16 copy
__global__ __launch_bounds__(256) void k_xs(const float* __restrict__ dt,
                                            const float* __restrict__ w,
                                            const float* __restrict__ bias,
                                            const float* __restrict__ x,
                                            const float* __restrict__ mask,
                                            const float* __restrict__ xmean,
                                            float* __restrict__ out_xs,
                                            unsigned short* __restrict__ out_bf) {
  __shared__ float As[64][17];
  __shared__ float Bs[16][64];
  int tid = threadIdx.x;
  int tx = tid & 15, ty = tid >> 4;
  int m0 = blockIdx.y * 64, n0 = blockIdx.x * 64;
  float acc[4][4] = {};
  for (int k0 = 0; k0 < Dn; k0 += 16) {
    {
      int ml = tid >> 2, kk = (tid & 3) * 4;
      float4 v = *(const float4*)(dt + (size_t)(m0 + ml) * Dn + k0 + kk);
      As[ml][kk + 0] = v.x; As[ml][kk + 1] = v.y;
      As[ml][kk + 2] = v.z; As[ml][kk + 3] = v.w;
    }
    {
      int kb = (tid >> 6) * 4, nl = tid & 63;
#pragma unroll
      for (int r = 0; r < 4; ++r)
        Bs[kb + r][nl] = w[(size_t)(k0 + kb + r) * Dn + n0 + nl];
    }
    __syncthreads();
#pragma unroll
    for (int kk = 0; kk < 16; ++kk) {
      float a[4], b[4];
#pragma unroll
      for (int i = 0; i < 4; ++i) a[i] = As[ty + 16 * i][kk];
#pragma unroll
      for (int j = 0; j < 4; ++j) b[j] = Bs[kk][tx + 16 * j];
#pragma unroll
      for (int i = 0; i < 4; ++i)
#pragma unroll
        for (int j = 0; j < 4; ++j) acc[i][j] += a[i] * b[j];
    }
    __syncthreads();
  }
#pragma unroll
  for (int j = 0; j < 4; ++j) {
    int d = n0 + tx + 16 * j;
    float bv = bias[d];
    float xm = xmean[d];
#pragma unroll
    for (int i = 0; i < 4; ++i) {
      int m = m0 + ty + 16 * i;
      int b = m >> 7, tt = m & (Tn - 1);
      float g = expf(-fmaxf(acc[i][j] + bv, 0.0f));
      float imput = (tt == 0) ? xm
                              : g * x[(size_t)(m - 1) * Dn + d] + (1.0f - g) * xm;
      float xv = x[(size_t)m * Dn + d];
      float mv = mask[(size_t)m * Dn + d];
      float xsv = xv * mv + (1.0f - mv) * imput;
      size_t oi = ((size_t)tt * Bn + b) * Dn + d;
      out_xs[oi] = xsv;
      out_bf[oi] = f2bf(xsv);
    }
  }
}

// hdec_bf[0][b][h] = bf16(h0[h] * gammaT[0][b][h]); zero flag array
__global__ __launch_bounds__(256) void k_init(const float* __restrict__ h0,
                                              const float* __restrict__ gammaT,
                                              unsigned short* __restrict__ hdec,
                                              int* __restrict__ bar) {
  int i = blockIdx.x * 256 + threadIdx.x;  // [0, Bn*Hn) = [0][b][h]
  int h = i & (Hn - 1);
  hdec[i] = f2bf(h0[h] * gammaT[i]);
  if (i < NGROUP * BLK_PER_GROUP * FLAG_STRIDE) bar[i] = 0;
}

// Persistent MFMA scan: 256 blocks (1/CU), 8 groups x 32 blocks.
// Block owns 32 batches x 16 h-units (64 gate cols). Weights bf16 in LDS.
// Cross-step exchange (hdec + flags) uses agent-scope atomics ONLY — no fences,
// no per-step cache writeback/invalidate; h_bf/xs/gammaT remain cached traffic.
__global__ __launch_bounds__(256, 1) void k_scan(
    const unsigned short* __restrict__ xs_bf,  // [T,B,D] bf16
    const float* __restrict__ gammaT,          // [T,B,H] fp32
    unsigned short* __restrict__ hdec_bf,      // [2,B,H] bf16 (pre-decayed h)
    unsigned short* __restrict__ h_bf,         // [T,B,H] bf16 (h1 history)
    const float* __restrict__ c0,              // [H]
    const float* __restrict__ W_ih,            // [4H, D] fp32
    const float* __restrict__ W_hh,            // [4H, H] fp32
    const float* __restrict__ b_ih, const float* __restrict__ b_hh,
    const float* __restrict__ tp,              // [B,T]
    const float* __restrict__ w_t, const float* __restrict__ h_t,
    int* __restrict__ bar) {
  __shared__ unsigned short Wlds[64 * AP];  // 97 KB: 64 gate cols x 768 K
  __shared__ unsigned short Alds[32 * AP];  // 48.5 KB: 32 batches x 768 K
  __shared__ float Gs[32 * GS];             // 8.7 KB
  int tid = threadIdx.x;
  int bt = blockIdx.x & 7;   // batch group (round-robin -> one XCD per group)
  int ht = blockIdx.x >> 3;  // h tile [0,32)
  int b0 = bt * 32, h0b = ht * 16;

  // --- stage weights once: col c = g*16 + hu, K-major bf16
  for (int idx = tid; idx < 64 * 192; idx += 256) {
    int c = idx / 192;
    int s = idx - c * 192;
    int kg = s * 4;
    int g = c >> 4, hu = c & 15;
    int jw = g * Hn + h0b + hu;
    float4 wv;
    if (kg < Dn) wv = *(const float4*)(W_ih + (size_t)jw * Dn + kg);
    else         wv = *(const float4*)(W_hh + (size_t)jw * Hn + (kg - Dn));
    unsigned int u01 = (unsigned int)f2bf(wv.x) | ((unsigned int)f2bf(wv.y) << 16);
    unsigned int u23 = (unsigned int)f2bf(wv.z) | ((unsigned int)f2bf(wv.w) << 16);
    *(unsigned int*)(&Wlds[(size_t)c * AP + kg]) = u01;
    *(unsigned int*)(&Wlds[(size_t)c * AP + kg + 2]) = u23;
  }

  // --- per-thread cell hoists: thread -> (batch bl, h-pair hp): 2 adjacent h
  int bl = tid >> 3;          // [0,32)
  int hp = tid & 7;           // h pair index
  int hloc = 2 * hp;          // local h unit of first cell
  int b = b0 + bl;
  float bias[4][2];
#pragma unroll
  for (int g = 0; g < 4; ++g)
#pragma unroll
    for (int u = 0; u < 2; ++u) {
      int jw = g * Hn + h0b + hloc + u;
      bias[g][u] = b_ih[jw] + b_hh[jw];
    }
  float wtv[2], htv[2], creg[2];
#pragma unroll
  for (int u = 0; u < 2; ++u) {
    wtv[u] = w_t[h0b + hloc + u];
    htv[u] = h_t[h0b + hloc + u];
    creg[u] = c0[h0b + hloc + u];
  }
  int* mybar = bar + bt * BLK_PER_GROUP * FLAG_STRIDE;

  // --- MFMA lane mapping: wave w -> M-half (w&1), N-group (w>>1)
  int lane = tid & 63, wv4 = tid >> 6;
  int ln = lane & 15, qd = lane >> 4;
  int mrow = 16 * (wv4 & 1) + ln;
  int ncol = 32 * (wv4 >> 1);
  const unsigned short* abase = &Alds[(size_t)mrow * AP + qd * 8];
  const unsigned short* bb0 = &Wlds[(size_t)(ncol + ln) * AP + qd * 8];
  const unsigned short* bb1 = &Wlds[(size_t)(ncol + 16 + ln) * AP + qd * 8];
  __syncthreads();

  for (int t = 0; t < Tn; ++t) {
    // --- prefetch epilogue operands (read-only streams, cached)
    float2 gam0 = *(const float2*)(gammaT + ((size_t)t * Bn + b) * Hn + h0b + hloc);
    float2 gam1 = (t + 1 < Tn)
        ? *(const float2*)(gammaT + ((size_t)(t + 1) * Bn + b) * Hn + h0b + hloc)
        : make_float2(0.f, 0.f);
    float tpv = tp[(size_t)b * Tn + t];

    // --- stage xs(t) rows (k < 256), cached loads
    {
      const float4* xsrc = (const float4*)(xs_bf + ((size_t)t * Bn + b0) * Dn);
#pragma unroll
      for (int i = 0; i < 4; ++i) {
        int c = tid + 256 * i;
        *(float4*)(&Alds[(size_t)(c >> 5) * AP + (c & 31) * 8]) = xsrc[c];
      }
    }

    // --- wait for group's previous step (skip at t=0)
    if (t > 0) {
      if (tid < BLK_PER_GROUP) {
        int spins = 0;
        while (__hip_atomic_load(&mybar[tid * FLAG_STRIDE], __ATOMIC_RELAXED,
                                 __HIP_MEMORY_SCOPE_AGENT) < t) {
          __builtin_amdgcn_s_sleep(1);
          if (++spins > 50000000) break;  // bail visibly rather than hang
        }
      }
      __syncthreads();
    }

    // --- pull pre-decayed h via agent-scope (cache-bypass) 8B atomic loads
    {
      const unsigned long long* hsrc = (const unsigned long long*)(
          hdec_bf + (size_t)(t & 1) * Bn * Hn + (size_t)b0 * Hn);
#pragma unroll
      for (int i = 0; i < 16; ++i) {
        int c = tid + 256 * i;  // [0, 4096) 8B units
        unsigned long long v = __hip_atomic_load(&hsrc[c], __ATOMIC_RELAXED,
                                                 __HIP_MEMORY_SCOPE_AGENT);
        *(unsigned long long*)(&Alds[(size_t)(c >> 7) * AP + 256 + (c & 127) * 4]) = v;
      }
    }
    __syncthreads();

    // --- MFMA: 24 k-steps x 2 n-tiles -> 16M x 32N per wave
    f32x4 acc0 = {0.f, 0.f, 0.f, 0.f};
    f32x4 acc1 = {0.f, 0.f, 0.f, 0.f};
#pragma unroll
    for (int ks = 0; ks < 24; ++ks) {
      bf8_t a = *(const bf8_t*)(abase + ks * 32);
      bf8_t b0f = *(const bf8_t*)(bb0 + ks * 32);
      bf8_t b1f = *(const bf8_t*)(bb1 + ks * 32);
      acc0 = __builtin_amdgcn_mfma_f32_16x16x32_bf16(a, b0f, acc0, 0, 0, 0);
      acc1 = __builtin_amdgcn_mfma_f32_16x16x32_bf16(a, b1f, acc1, 0, 0, 0);
    }

    // --- gates -> LDS (C layout: col=lane&15, row=quad*4+reg)
#pragma unroll
    for (int r = 0; r < 4; ++r) {
      int grow = 16 * (wv4 & 1) + qd * 4 + r;
      Gs[grow * GS + ncol + ln] = acc0[r];
      Gs[grow * GS + ncol + 16 + ln] = acc1[r];
    }
    __syncthreads();

    // --- LSTM cell: 2 adjacent-h cells per thread
    {
      float2 ip = *(const float2*)(&Gs[bl * GS + hloc]);
      float2 fp = *(const float2*)(&Gs[bl * GS + 16 + hloc]);
      float2 gp = *(const float2*)(&Gs[bl * GS + 32 + hloc]);
      float2 op = *(const float2*)(&Gs[bl * GS + 48 + hloc]);
      float h1[2], hd[2];
      float gam0a[2] = {gam0.x, gam0.y}, gam1a[2] = {gam1.x, gam1.y};
      float ipa[2] = {ip.x, ip.y}, fpa[2] = {fp.x, fp.y};
      float gpa[2] = {gp.x, gp.y}, opa[2] = {op.x, op.y};
#pragma unroll
      for (int u = 0; u < 2; ++u) {
        float c1 = sigm(fpa[u] + bias[1][u]) * (creg[u] * gam0a[u]) +
                   sigm(ipa[u] + bias[0][u]) * tanhf(gpa[u] + bias[2][u]);
        float gtv = sigm(tpv * wtv[u] + htv[u]);
        h1[u] = gtv * sigm(opa[u] + bias[3][u]) * tanhf(c1);
        creg[u] = gtv * c1;
        hd[u] = h1[u] * gam1a[u];
      }
      unsigned int hpk = (unsigned int)f2bf(h1[0]) | ((unsigned int)f2bf(h1[1]) << 16);
      *(unsigned int*)(h_bf + ((size_t)t * Bn + b) * Hn + h0b + hloc) = hpk;
      if (t + 1 < Tn) {
        unsigned int dpk =
            (unsigned int)f2bf(hd[0]) | ((unsigned int)f2bf(hd[1]) << 16);
        unsigned int* dst = (unsigned int*)(
            hdec_bf + (size_t)((t + 1) & 1) * Bn * Hn + (size_t)b * Hn + h0b + hloc);
        __hip_atomic_store(dst, dpk, __ATOMIC_RELAXED, __HIP_MEMORY_SCOPE_AGENT);
      }
    }

    if (t + 1 < Tn) {
      __syncthreads();  // workgroup fence: every thread's stores vmcnt-drained
      if (tid == 0)
        __hip_atomic_store(&mybar[ht * FLAG_STRIDE], t + 1, __ATOMIC_RELEASE,
                           __HIP_MEMORY_SCOPE_AGENT);
    }
  }
}

// Batched output head over all (t,b) rows; h1 read from bf16 history
__global__ __launch_bounds__(256) void k_head(const unsigned short* __restrict__ h_bf,
                                              const float* __restrict__ W1,
                                              const float* __restrict__ b1,
                                              const float* __restrict__ W2,
                                              const float* __restrict__ b2,
                                              float* __restrict__ outs) {
  __shared__ float sW1[Hn * 10];
  for (int i = threadIdx.x; i < Hn * 10; i += 256) sW1[i] = W1[i];
  __syncthreads();
  int idx = blockIdx.x * 256 + threadIdx.x;  // idx = tt*Bn + b
  const uint4* row = (const uint4*)(h_bf + (size_t)idx * Hn);
  float z1[10];
#pragma unroll
  for (int k = 0; k < 10; ++k) z1[k] = b1[k];
  for (int hq = 0; hq < Hn / 8; ++hq) {
    uint4 u = row[hq];
    float hv[8];
    hv[0] = bf2f(u.x & 0xffff); hv[1] = bf2f(u.x >> 16);
    hv[2] = bf2f(u.y & 0xffff); hv[3] = bf2f(u.y >> 16);
    hv[4] = bf2f(u.z & 0xffff); hv[5] = bf2f(u.z >> 16);
    hv[6] = bf2f(u.w & 0xffff); hv[7] = bf2f(u.w >> 16);
    int hb = hq * 8;
#pragma unroll
    for (int c = 0; c < 8; ++c)
#pragma unroll
      for (int k = 0; k < 10; ++k) z1[k] += hv[c] * sW1[(hb + c) * 10 + k];
  }
#pragma unroll
  for (int k = 0; k < 10; ++k) z1[k] = sigm(z1[k]);
  float z2[2];
#pragma unroll
  for (int c = 0; c < 2; ++c) {
    float v = b2[c];
#pragma unroll
    for (int k = 0; k < 10; ++k) v += z1[k] * W2[k * 2 + c];
    z2[c] = sigm(v);
  }
  float mx = fmaxf(z2[0], z2[1]);
  float e0 = expf(z2[0] - mx), e1 = expf(z2[1] - mx);
  float s = e0 + e1;
  outs[(size_t)idx * 2 + 0] = e0 / s;
  outs[(size_t)idx * 2 + 1] = e1 / s;
}

}  // namespace

extern "C" void kernel_launch(void* const* d_in, const int* in_sizes, int n_in,
                              void* d_out, int out_size, void* d_ws,
                              size_t ws_size, hipStream_t stream) {
  (void)in_sizes; (void)n_in; (void)out_size; (void)ws_size;
  const float* x     = (const float*)d_in[0];
  const float* dt    = (const float*)d_in[1];
  const float* mask  = (const float*)d_in[2];
  const float* tp    = (const float*)d_in[3];
  const float* xmean = (const float*)d_in[4];
  const float* h0    = (const float*)d_in[5];
  const float* c0    = (const float*)d_in[6];
  const float* w_gx  = (const float*)d_in[7];
  const float* h_gx  = (const float*)d_in[8];
  const float* w_gh  = (const float*)d_in[9];
  const float* h_gh  = (const float*)d_in[10];
  const float* w_t   = (const float*)d_in[11];
  const float* h_t   = (const float*)d_in[12];
  const float* W_ih  = (const float*)d_in[13];
  const float* W_hh  = (const float*)d_in[14];
  const float* b_ih  = (const float*)d_in[15];
  const float* b_hh  = (const float*)d_in[16];
  const float* oW1   = (const float*)d_in[17];
  const float* ob1   = (const float*)d_in[18];
  const float* oW2   = (const float*)d_in[19];
  const float* ob2   = (const float*)d_in[20];

  float* out  = (float*)d_out;
  float* outs = out;                        // [T,B,2]
  float* xhat = out + (size_t)Tn * Bn * 2;  // [T,B,D] fp32 (output 1)

  float* ws = (float*)d_ws;
  float* gammaT = ws;  // [T,B,H] fp32: 67.1 MB
  unsigned short* xs_bf   = (unsigned short*)(gammaT + (size_t)BT * Hn);  // 16.8 MB
  unsigned short* h_bf    = xs_bf + (size_t)BT * Dn;                      // 33.6 MB
  unsigned short* hdec_bf = h_bf + (size_t)BT * Hn;                       // 0.5 MB
  int* bar = (int*)(hdec_bf + 2 * (size_t)Bn * Hn);                       // 32 KB flags

  k_gamma_h<<<dim3(Hn / 64, BT / 64), 256, 0, stream>>>(dt, w_gh, h_gh, gammaT);
  k_xs<<<dim3(Dn / 64, BT / 64), 256, 0, stream>>>(dt, w_gx, h_gx, x, mask,
                                                   xmean, xhat, xs_bf);
  k_init<<<(Bn * Hn) / 256, 256, 0, stream>>>(h0, gammaT, hdec_bf, bar);
  k_scan<<<256, 256, 0, stream>>>(xs_bf, gammaT, hdec_bf, h_bf, c0, W_ih, W_hh,
                                  b_ih, b_hh, tp, w_t, h_t, bar);
  k_head<<<BT / 256, 256, 0, stream>>>(h_bf, oW1, ob1, oW2, ob2, outs);
}

// Round 6
// 1301.273 us; speedup vs baseline: 4.0627x; 1.2706x over previous
//
#include <hip/hip_runtime.h>
#include <hip/hip_bf16.h>
#include <math.h>

namespace {

constexpr int Bn = 256;
constexpr int Tn = 128;
constexpr int Dn = 256;
constexpr int Hn = 512;
constexpr int BT = Bn * Tn;

constexpr int AP = 776;   // scan LDS K-stride in bf16 (768+8)
constexpr int GP = 264;   // gamma LDS K-stride in bf16 (256+8)
constexpr int GS = 68;    // gate tile stride (floats)
constexpr int FLAG_STRIDE = 32;
constexpr int NGROUP = 8;
constexpr int BLK_PER_GROUP = 32;

typedef short bf8_t __attribute__((ext_vector_type(8)));
typedef float f32x4 __attribute__((ext_vector_type(4)));
typedef unsigned int u32x4 __attribute__((ext_vector_type(4)));

__device__ __forceinline__ float sigm(float v) { return 1.0f / (1.0f + expf(-v)); }

__device__ __forceinline__ unsigned short f2bf(float f) {
  union { __hip_bfloat16 h; unsigned short u; } v;
  v.h = __float2bfloat16(f);
  return v.u;
}
__device__ __forceinline__ float bf2f(unsigned short u) {
  union { unsigned int i; float f; } v;
  v.i = ((unsigned int)u) << 16;
  return v.f;
}

// dt fp32 -> bf16 (flat copy)
__global__ __launch_bounds__(256) void k_cvt_dt(const float* __restrict__ src,
                                                unsigned short* __restrict__ dst) {
  size_t i = (size_t)blockIdx.x * 256 + threadIdx.x;
  float4 v = ((const float4*)src)[i];
  uint2 o;
  o.x = (unsigned)f2bf(v.x) | ((unsigned)f2bf(v.y) << 16);
  o.y = (unsigned)f2bf(v.z) | ((unsigned)f2bf(v.w) << 16);
  ((uint2*)dst)[i] = o;
}

// w_gh [Dn,Hn] fp32 -> wT bf16 [Hn,Dn] (transpose)
__global__ __launch_bounds__(256) void k_cvt_wgh(const float* __restrict__ w,
                                                 unsigned short* __restrict__ wT) {
  int o = blockIdx.x * 256 + threadIdx.x;  // = n*Dn + k
  int n = o >> 8, k = o & 255;
  wT[o] = f2bf(w[(size_t)k * Hn + n]);
}

// gamma_h via MFMA: [BT,256]bf16 @ [256,512] -> exp(-relu(.+bias)) into [T,B,H] fp32
__global__ __launch_bounds__(256) void k_gamma_mfma(
    const unsigned short* __restrict__ dtb,  // [BT, Dn] bf16
    const unsigned short* __restrict__ wT,   // [Hn, Dn] bf16
    const float* __restrict__ bias,          // [Hn]
    float* __restrict__ outg) {              // [T,B,H]
  __shared__ unsigned short Abf[128 * GP];  // 67.6 KB
  __shared__ unsigned short Bbf[64 * GP];   // 33.8 KB
  int tid = threadIdx.x;
  int n0 = blockIdx.x * 64;
  int bb = blockIdx.y;  // one 128-row M-block == one batch
  const u32x4* asrc = (const u32x4*)(dtb + (size_t)bb * 128 * Dn);
#pragma unroll
  for (int i = 0; i < 16; ++i) {
    int c = tid + 256 * i;
    *(u32x4*)(&Abf[(size_t)(c >> 5) * GP + (c & 31) * 8]) = asrc[c];
  }
  const u32x4* bsrc = (const u32x4*)(wT + (size_t)n0 * Dn);
#pragma unroll
  for (int i = 0; i < 8; ++i) {
    int c = tid + 256 * i;
    *(u32x4*)(&Bbf[(size_t)(c >> 5) * GP + (c & 31) * 8]) = bsrc[c];
  }
  int lane = tid & 63, w = tid >> 6;
  int ln = lane & 15, qd = lane >> 4;
  float bn[4];
#pragma unroll
  for (int j = 0; j < 4; ++j) bn[j] = bias[n0 + 16 * j + ln];
  __syncthreads();
  f32x4 acc[2][4] = {};
  const unsigned short* a0 = &Abf[(size_t)(32 * w + ln) * GP + qd * 8];
  const unsigned short* a1 = &Abf[(size_t)(32 * w + 16 + ln) * GP + qd * 8];
#pragma unroll
  for (int ks = 0; ks < 8; ++ks) {
    bf8_t af0 = *(const bf8_t*)(a0 + ks * 32);
    bf8_t af1 = *(const bf8_t*)(a1 + ks * 32);
#pragma unroll
    for (int j = 0; j < 4; ++j) {
      bf8_t bf = *(const bf8_t*)(&Bbf[(size_t)(16 * j + ln) * GP + qd * 8 + ks * 32]);
      acc[0][j] = __builtin_amdgcn_mfma_f32_16x16x32_bf16(af0, bf, acc[0][j], 0, 0, 0);
      acc[1][j] = __builtin_amdgcn_mfma_f32_16x16x32_bf16(af1, bf, acc[1][j], 0, 0, 0);
    }
  }
#pragma unroll
  for (int mt = 0; mt < 2; ++mt)
#pragma unroll
    for (int r = 0; r < 4; ++r) {
      int t = 32 * w + 16 * mt + qd * 4 + r;
#pragma unroll
      for (int j = 0; j < 4; ++j) {
        float v = acc[mt][j][r] + bn[j];
        outg[((size_t)t * Bn + bb) * Hn + n0 + 16 * j + ln] = expf(-fmaxf(v, 0.f));
      }
    }
}

// gamma_x GEMM fused with imputation; writes xs fp32 to xhats [T,B,D] and bf16 copy
__global__ __launch_bounds__(256) void k_xs(const float* __restrict__ dt,
                                            const float* __restrict__ w,
                                            const float* __restrict__ bias,
                                            const float* __restrict__ x,
                                            const float* __restrict__ mask,
                                            const float* __restrict__ xmean,
                                            float* __restrict__ out_xs,
                                            unsigned short* __restrict__ out_bf) {
  __shared__ float As[64][17];
  __shared__ float Bs[16][64];
  int tid = threadIdx.x;
  int tx = tid & 15, ty = tid >> 4;
  int m0 = blockIdx.y * 64, n0 = blockIdx.x * 64;
  float acc[4][4] = {};
  for (int k0 = 0; k0 < Dn; k0 += 16) {
    {
      int ml = tid >> 2, kk = (tid & 3) * 4;
      float4 v = *(const float4*)(dt + (size_t)(m0 + ml) * Dn + k0 + kk);
      As[ml][kk + 0] = v.x; As[ml][kk + 1] = v.y;
      As[ml][kk + 2] = v.z; As[ml][kk + 3] = v.w;
    }
    {
      int kb = (tid >> 6) * 4, nl = tid & 63;
#pragma unroll
      for (int r = 0; r < 4; ++r)
        Bs[kb + r][nl] = w[(size_t)(k0 + kb + r) * Dn + n0 + nl];
    }
    __syncthreads();
#pragma unroll
    for (int kk = 0; kk < 16; ++kk) {
      float a[4], b[4];
#pragma unroll
      for (int i = 0; i < 4; ++i) a[i] = As[ty + 16 * i][kk];
#pragma unroll
      for (int j = 0; j < 4; ++j) b[j] = Bs[kk][tx + 16 * j];
#pragma unroll
      for (int i = 0; i < 4; ++i)
#pragma unroll
        for (int j = 0; j < 4; ++j) acc[i][j] += a[i] * b[j];
    }
    __syncthreads();
  }
#pragma unroll
  for (int j = 0; j < 4; ++j) {
    int d = n0 + tx + 16 * j;
    float bv = bias[d];
    float xm = xmean[d];
#pragma unroll
    for (int i = 0; i < 4; ++i) {
      int m = m0 + ty + 16 * i;
      int b = m >> 7, tt = m & (Tn - 1);
      float g = expf(-fmaxf(acc[i][j] + bv, 0.0f));
      float imput = (tt == 0) ? xm
                              : g * x[(size_t)(m - 1) * Dn + d] + (1.0f - g) * xm;
      float xv = x[(size_t)m * Dn + d];
      float mv = mask[(size_t)m * Dn + d];
      float xsv = xv * mv + (1.0f - mv) * imput;
      size_t oi = ((size_t)tt * Bn + b) * Dn + d;
      out_xs[oi] = xsv;
      out_bf[oi] = f2bf(xsv);
    }
  }
}

// hdec_bf[0][b][h] = bf16(h0[h] * gammaT[0][b][h]); zero flag array
__global__ __launch_bounds__(256) void k_init(const float* __restrict__ h0,
                                              const float* __restrict__ gammaT,
                                              unsigned short* __restrict__ hdec,
                                              int* __restrict__ bar) {
  int i = blockIdx.x * 256 + threadIdx.x;  // [0, Bn*Hn) = [0][b][h]
  int h = i & (Hn - 1);
  hdec[i] = f2bf(h0[h] * gammaT[i]);
  if (i < NGROUP * BLK_PER_GROUP * FLAG_STRIDE) bar[i] = 0;
}

// Persistent MFMA scan: 256 blocks, 8 groups x 32 blocks.
// Block owns 32 batches x 16 h-units. Weights bf16 in LDS. Cross-step hdec
// exchange via inline-asm sc0/sc1 (cache-bypassing, PIPELINED) loads/stores;
// flags via one agent atomic per block. No fences in the loop.
__global__ __launch_bounds__(256, 1) void k_scan(
    const unsigned short* __restrict__ xs_bf,  // [T,B,D] bf16
    const float* __restrict__ gammaT,          // [T,B,H] fp32
    unsigned short* __restrict__ hdec_bf,      // [2,B,H] bf16 (pre-decayed h)
    unsigned short* __restrict__ h_bf,         // [T,B,H] bf16 (h1 history)
    const float* __restrict__ c0,              // [H]
    const float* __restrict__ W_ih,            // [4H, D] fp32
    const float* __restrict__ W_hh,            // [4H, H] fp32
    const float* __restrict__ b_ih, const float* __restrict__ b_hh,
    const float* __restrict__ tp,              // [B,T]
    const float* __restrict__ w_t, const float* __restrict__ h_t,
    int* __restrict__ bar) {
  __shared__ unsigned short Wlds[64 * AP];  // 97 KB: 64 gate cols x 768 K
  __shared__ unsigned short Alds[32 * AP];  // 48.5 KB: 32 batches x 768 K
  __shared__ float Gs[32 * GS];             // 8.7 KB
  int tid = threadIdx.x;
  int bt = blockIdx.x & 7;   // batch group
  int ht = blockIdx.x >> 3;  // h tile [0,32)
  int b0 = bt * 32, h0b = ht * 16;

  // --- stage weights once: col c = g*16 + hu, K-major bf16
  for (int idx = tid; idx < 64 * 192; idx += 256) {
    int c = idx / 192;
    int s = idx - c * 192;
    int kg = s * 4;
    int g = c >> 4, hu = c & 15;
    int jw = g * Hn + h0b + hu;
    float4 wv;
    if (kg < Dn) wv = *(const float4*)(W_ih + (size_t)jw * Dn + kg);
    else         wv = *(const float4*)(W_hh + (size_t)jw * Hn + (kg - Dn));
    unsigned int u01 = (unsigned int)f2bf(wv.x) | ((unsigned int)f2bf(wv.y) << 16);
    unsigned int u23 = (unsigned int)f2bf(wv.z) | ((unsigned int)f2bf(wv.w) << 16);
    *(unsigned int*)(&Wlds[(size_t)c * AP + kg]) = u01;
    *(unsigned int*)(&Wlds[(size_t)c * AP + kg + 2]) = u23;
  }

  // --- per-thread cell hoists: thread -> (batch bl, h-pair hp)
  int bl = tid >> 3;
  int hp = tid & 7;
  int hloc = 2 * hp;
  int b = b0 + bl;
  float bias[4][2];
#pragma unroll
  for (int g = 0; g < 4; ++g)
#pragma unroll
    for (int u = 0; u < 2; ++u) {
      int jw = g * Hn + h0b + hloc + u;
      bias[g][u] = b_ih[jw] + b_hh[jw];
    }
  float wtv[2], htv[2], creg[2];
#pragma unroll
  for (int u = 0; u < 2; ++u) {
    wtv[u] = w_t[h0b + hloc + u];
    htv[u] = h_t[h0b + hloc + u];
    creg[u] = c0[h0b + hloc + u];
  }
  int* mybar = bar + bt * BLK_PER_GROUP * FLAG_STRIDE;

  // --- MFMA lane mapping
  int lane = tid & 63, wv4 = tid >> 6;
  int ln = lane & 15, qd = lane >> 4;
  int mrow = 16 * (wv4 & 1) + ln;
  int ncol = 32 * (wv4 >> 1);
  const unsigned short* abase = &Alds[(size_t)mrow * AP + qd * 8];
  const unsigned short* bb0 = &Wlds[(size_t)(ncol + ln) * AP + qd * 8];
  const unsigned short* bb1 = &Wlds[(size_t)(ncol + 16 + ln) * AP + qd * 8];
  __syncthreads();

  for (int t = 0; t < Tn; ++t) {
    // --- prefetch epilogue operands (cached)
    float2 gam0 = *(const float2*)(gammaT + ((size_t)t * Bn + b) * Hn + h0b + hloc);
    float2 gam1 = (t + 1 < Tn)
        ? *(const float2*)(gammaT + ((size_t)(t + 1) * Bn + b) * Hn + h0b + hloc)
        : make_float2(0.f, 0.f);
    float tpv = tp[(size_t)b * Tn + t];

    // --- stage xs(t) rows (k < 256), cached loads
    {
      const float4* xsrc = (const float4*)(xs_bf + ((size_t)t * Bn + b0) * Dn);
#pragma unroll
      for (int i = 0; i < 4; ++i) {
        int c = tid + 256 * i;
        *(float4*)(&Alds[(size_t)(c >> 5) * AP + (c & 31) * 8]) = xsrc[c];
      }
    }

    // --- wait for group's previous step
    if (t > 0) {
      if (tid < BLK_PER_GROUP) {
        int spins = 0;
        while (__hip_atomic_load(&mybar[tid * FLAG_STRIDE], __ATOMIC_RELAXED,
                                 __HIP_MEMORY_SCOPE_AGENT) < t) {
          __builtin_amdgcn_s_sleep(1);
          if (++spins > 50000000) break;  // bail visibly rather than hang
        }
      }
      __syncthreads();
    }

    // --- pull pre-decayed h: pipelined cache-bypassing dwordx4 loads
    {
      const unsigned short* hsrc =
          hdec_bf + (size_t)(t & 1) * Bn * Hn + (size_t)b0 * Hn;
      u32x4 hv[8];
#pragma unroll
      for (int i = 0; i < 8; ++i) {
        const void* p = hsrc + (size_t)(tid + 256 * i) * 8;  // 16 B units
        asm volatile("global_load_dwordx4 %0, %1, off sc0 sc1"
                     : "=v"(hv[i]) : "v"(p) : "memory");
      }
      asm volatile("s_waitcnt vmcnt(0)" ::: "memory");
#pragma unroll
      for (int i = 0; i < 8; ++i) {
        int c = tid + 256 * i;
        *(u32x4*)(&Alds[(size_t)(c >> 6) * AP + 256 + (c & 63) * 8]) = hv[i];
      }
    }
    __syncthreads();

    // --- MFMA: 24 k-steps x 2 n-tiles -> 16M x 32N per wave
    f32x4 acc0 = {0.f, 0.f, 0.f, 0.f};
    f32x4 acc1 = {0.f, 0.f, 0.f, 0.f};
#pragma unroll
    for (int ks = 0; ks < 24; ++ks) {
      bf8_t a = *(const bf8_t*)(abase + ks * 32);
      bf8_t b0f = *(const bf8_t*)(bb0 + ks * 32);
      bf8_t b1f = *(const bf8_t*)(bb1 + ks * 32);
      acc0 = __builtin_amdgcn_mfma_f32_16x16x32_bf16(a, b0f, acc0, 0, 0, 0);
      acc1 = __builtin_amdgcn_mfma_f32_16x16x32_bf16(a, b1f, acc1, 0, 0, 0);
    }

    // --- gates -> LDS (C layout: col=lane&15, row=quad*4+reg)
#pragma unroll
    for (int r = 0; r < 4; ++r) {
      int grow = 16 * (wv4 & 1) + qd * 4 + r;
      Gs[grow * GS + ncol + ln] = acc0[r];
      Gs[grow * GS + ncol + 16 + ln] = acc1[r];
    }
    __syncthreads();

    // --- LSTM cell: 2 adjacent-h cells per thread
    {
      float2 ip = *(const float2*)(&Gs[bl * GS + hloc]);
      float2 fp = *(const float2*)(&Gs[bl * GS + 16 + hloc]);
      float2 gp = *(const float2*)(&Gs[bl * GS + 32 + hloc]);
      float2 op = *(const float2*)(&Gs[bl * GS + 48 + hloc]);
      float h1[2], hd[2];
      float gam0a[2] = {gam0.x, gam0.y}, gam1a[2] = {gam1.x, gam1.y};
      float ipa[2] = {ip.x, ip.y}, fpa[2] = {fp.x, fp.y};
      float gpa[2] = {gp.x, gp.y}, opa[2] = {op.x, op.y};
#pragma unroll
      for (int u = 0; u < 2; ++u) {
        float c1 = sigm(fpa[u] + bias[1][u]) * (creg[u] * gam0a[u]) +
                   sigm(ipa[u] + bias[0][u]) * tanhf(gpa[u] + bias[2][u]);
        float gtv = sigm(tpv * wtv[u] + htv[u]);
        h1[u] = gtv * sigm(opa[u] + bias[3][u]) * tanhf(c1);
        creg[u] = gtv * c1;
        hd[u] = h1[u] * gam1a[u];
      }
      unsigned int hpk = (unsigned int)f2bf(h1[0]) | ((unsigned int)f2bf(h1[1]) << 16);
      *(unsigned int*)(h_bf + ((size_t)t * Bn + b) * Hn + h0b + hloc) = hpk;
      if (t + 1 < Tn) {
        unsigned int dpk =
            (unsigned int)f2bf(hd[0]) | ((unsigned int)f2bf(hd[1]) << 16);
        const void* dp = hdec_bf + (size_t)((t + 1) & 1) * Bn * Hn +
                         (size_t)b * Hn + h0b + hloc;
        asm volatile("global_store_dword %0, %1, off sc0 sc1"
                     :: "v"(dp), "v"(dpk) : "memory");
      }
    }

    if (t + 1 < Tn) {
      asm volatile("s_waitcnt vmcnt(0)" ::: "memory");  // drain hdec/h_bf stores
      __syncthreads();
      if (tid == 0)
        __hip_atomic_store(&mybar[ht * FLAG_STRIDE], t + 1, __ATOMIC_RELEASE,
                           __HIP_MEMORY_SCOPE_AGENT);
    }
  }
}

// Batched output head over all (t,b) rows; h1 read from bf16 history
__global__ __launch_bounds__(256) void k_head(const unsigned short* __restrict__ h_bf,
                                              const float* __restrict__ W1,
                                              const float* __restrict__ b1,
                                              const float* __restrict__ W2,
                                              const float* __restrict__ b2,
                                              float* __restrict__ outs) {
  __shared__ float sW1[Hn * 10];
  for (int i = threadIdx.x; i < Hn * 10; i += 256) sW1[i] = W1[i];
  __syncthreads();
  int idx = blockIdx.x * 256 + threadIdx.x;  // idx = tt*Bn + b
  const uint4* row = (const uint4*)(h_bf + (size_t)idx * Hn);
  float z1[10];
#pragma unroll
  for (int k = 0; k < 10; ++k) z1[k] = b1[k];
  for (int hq = 0; hq < Hn / 8; ++hq) {
    uint4 u = row[hq];
    float hv[8];
    hv[0] = bf2f(u.x & 0xffff); hv[1] = bf2f(u.x >> 16);
    hv[2] = bf2f(u.y & 0xffff); hv[3] = bf2f(u.y >> 16);
    hv[4] = bf2f(u.z & 0xffff); hv[5] = bf2f(u.z >> 16);
    hv[6] = bf2f(u.w & 0xffff); hv[7] = bf2f(u.w >> 16);
    int hb = hq * 8;
#pragma unroll
    for (int c = 0; c < 8; ++c)
#pragma unroll
      for (int k = 0; k < 10; ++k) z1[k] += hv[c] * sW1[(hb + c) * 10 + k];
  }
#pragma unroll
  for (int k = 0; k < 10; ++k) z1[k] = sigm(z1[k]);
  float z2[2];
#pragma unroll
  for (int c = 0; c < 2; ++c) {
    float v = b2[c];
#pragma unroll
    for (int k = 0; k < 10; ++k) v += z1[k] * W2[k * 2 + c];
    z2[c] = sigm(v);
  }
  float mx = fmaxf(z2[0], z2[1]);
  float e0 = expf(z2[0] - mx), e1 = expf(z2[1] - mx);
  float s = e0 + e1;
  outs[(size_t)idx * 2 + 0] = e0 / s;
  outs[(size_t)idx * 2 + 1] = e1 / s;
}

}  // namespace

extern "C" void kernel_launch(void* const* d_in, const int* in_sizes, int n_in,
                              void* d_out, int out_size, void* d_ws,
                              size_t ws_size, hipStream_t stream) {
  (void)in_sizes; (void)n_in; (void)out_size; (void)ws_size;
  const float* x     = (const float*)d_in[0];
  const float* dt    = (const float*)d_in[1];
  const float* mask  = (const float*)d_in[2];
  const float* tp    = (const float*)d_in[3];
  const float* xmean = (const float*)d_in[4];
  const float* h0    = (const float*)d_in[5];
  const float* c0    = (const float*)d_in[6];
  const float* w_gx  = (const float*)d_in[7];
  const float* h_gx  = (const float*)d_in[8];
  const float* w_gh  = (const float*)d_in[9];
  const float* h_gh  = (const float*)d_in[10];
  const float* w_t   = (const float*)d_in[11];
  const float* h_t   = (const float*)d_in[12];
  const float* W_ih  = (const float*)d_in[13];
  const float* W_hh  = (const float*)d_in[14];
  const float* b_ih  = (const float*)d_in[15];
  const float* b_hh  = (const float*)d_in[16];
  const float* oW1   = (const float*)d_in[17];
  const float* ob1   = (const float*)d_in[18];
  const float* oW2   = (const float*)d_in[19];
  const float* ob2   = (const float*)d_in[20];

  float* out  = (float*)d_out;
  float* outs = out;                        // [T,B,2]
  float* xhat = out + (size_t)Tn * Bn * 2;  // [T,B,D] fp32 (output 1)

  float* ws = (float*)d_ws;
  float* gammaT = ws;  // [T,B,H] fp32: 67.1 MB
  unsigned short* xs_bf   = (unsigned short*)(gammaT + (size_t)BT * Hn);  // 16.8 MB
  unsigned short* h_bf    = xs_bf + (size_t)BT * Dn;                      // 33.6 MB
  unsigned short* hdec_bf = h_bf + (size_t)BT * Hn;                       // 0.5 MB
  unsigned short* dt_bf   = hdec_bf + 2 * (size_t)Bn * Hn;                // 16.8 MB
  unsigned short* wghT    = dt_bf + (size_t)BT * Dn;                      // 0.26 MB
  int* bar = (int*)(wghT + (size_t)Hn * Dn);                              // 32 KB flags

  k_cvt_dt<<<BT * Dn / 4 / 256, 256, 0, stream>>>(dt, dt_bf);
  k_cvt_wgh<<<Hn * Dn / 256, 256, 0, stream>>>(w_gh, wghT);
  k_gamma_mfma<<<dim3(Hn / 64, Bn), 256, 0, stream>>>(dt_bf, wghT, h_gh, gammaT);
  k_xs<<<dim3(Dn / 64, BT / 64), 256, 0, stream>>>(dt, w_gx, h_gx, x, mask,
                                                   xmean, xhat, xs_bf);
  k_init<<<(Bn * Hn) / 256, 256, 0, stream>>>(h0, gammaT, hdec_bf, bar);
  k_scan<<<256, 256, 0, stream>>>(xs_bf, gammaT, hdec_bf, h_bf, c0, W_ih, W_hh,
                                  b_ih, b_hh, tp, w_t, h_t, bar);
  k_head<<<BT / 256, 256, 0, stream>>>(h_bf, oW1, ob1, oW2, ob2, outs);
}